// Round 5
// baseline (562.623 us; speedup 1.0000x reference)
//
#include <hip/hip_runtime.h>

// Model: e = maxpool_L(relu(x @ Wc^T + bc)); feat = [e1-e2, e1*e2];
//        h = tanh(feat @ W1^T + b1); out = h @ W2^T + b2   (all fp32 I/O)
// Sizes: B=2048, L=64, D=300, C=512, H=2048, O=1.
// R8 post-mortem (455us, first win): B-in-registers worked (no L2 thrash,
//   no spill) but SQ_LDS_BANK_CONFLICT=5e7 (~39% of encode): fp32 strided
//   A-reads at 1200B pitch + gload_lds 1KB DMA bursts colliding with reads.
//   R6's fragment-sequential bf16 LDS measured ~0 conflicts; its failure was
//   only the 40-VGPR staging spill.
// R9: merge the proven pieces. Keep B resident in 160 VGPR/wave (R8) +
//   sequential-mt acc reuse; stage x as bf16 into R6's conflict-free
//   fragment-sequential layout xs[mt][kc][l16][8] via reg-staging with
//   BOUNDED depth: two 5-deep float4 groups (20 VGPR held per compute
//   half, T14 split: load group A -> compute mt0-1 -> write A, load B ->
//   compute mt2-3 -> write B). Consumer A-read = one linear 1KB
//   ds_read_b128 per (mt,ks). cvt once per element (not per wave).
//   LDS 86KB = 2 x 40,960B bf16 tile + 4KB fs. One barrier per tile.
//   Budget/tile/CU: HBM 7.5K cyc >> LDS 5K >> MFMA 1.5K -> HBM-bound.

#define B_SZ 2048
#define L_SZ 64
#define D_SZ 300
#define C_SZ 512
#define H_SZ 2048
#define NKC 40            // K-chunks (8 bf16) per row, K padded 300->320

typedef __bf16 bf16x8 __attribute__((ext_vector_type(8)));
typedef __bf16 bf16x4 __attribute__((ext_vector_type(4)));
typedef float f32x4 __attribute__((ext_vector_type(4)));

__device__ __forceinline__ unsigned short f2bf(float f) {
  unsigned int u = __float_as_uint(f);
  u += 0x7fffu + ((u >> 16) & 1u);   // RNE
  return (unsigned short)(u >> 16);
}

// ---- kernel 0: build swizzled bf16 weights + init out = b2.
// WcSwz[(c/16)*40 + kc][l16=c%16][8]  (zero-pad k>=300)
// W1Swz[(j/16)*128 + kc][l16=j%16][8]
__global__ __launch_bounds__(256)
void convert_kernel(const float* __restrict__ Wc, const float* __restrict__ W1,
                    const float* __restrict__ b2,
                    unsigned short* __restrict__ WcSwz, unsigned short* __restrict__ W1Swz,
                    float* __restrict__ out) {
  int id = blockIdx.x * 256 + threadIdx.x;
  if (id < B_SZ) out[id] = b2[0];             // fc1 accumulates into out
  if (id < C_SZ * NKC) {                      // 20480 threads: (c, kc)
    int c = id / NKC, kc = id - c * NKC;
    unsigned short tmp[8];
    #pragma unroll
    for (int i = 0; i < 8; ++i) {
      int k = kc * 8 + i;
      tmp[i] = (k < D_SZ) ? f2bf(Wc[c * D_SZ + k]) : (unsigned short)0;
    }
    unsigned short* dst = WcSwz + (((c >> 4) * NKC + kc) * 16 + (c & 15)) * 8;
    *reinterpret_cast<uint4*>(dst) = *reinterpret_cast<uint4*>(tmp);
    return;
  }
  id -= C_SZ * NKC;
  if (id < H_SZ * 128) {                      // 262144 threads: (j, kc)
    int j = id >> 7, kc = id & 127;
    const float* src = W1 + (size_t)j * 1024 + kc * 8;
    unsigned short tmp[8];
    #pragma unroll
    for (int i = 0; i < 8; ++i) tmp[i] = f2bf(src[i]);
    unsigned short* dst = W1Swz + (((j >> 4) * 128 + kc) * 16 + (j & 15)) * 8;
    *reinterpret_cast<uint4*>(dst) = *reinterpret_cast<uint4*>(tmp);
  }
}

// ---- kernel 1: persistent encode + feat. 256 blocks (1/CU), 512 threads.
// Block handles b = bid + 256*i, i<8; per b two tiles (z=0,1), 16 tiles,
// bf16 fragment-sequential double-buffered LDS. Wave w owns channels
// [w*64, w*64+64) with weights resident in 160 VGPRs.
__global__ __launch_bounds__(512, 2)
void encode_feat_kernel(const float* __restrict__ x1, const float* __restrict__ x2,
                        const unsigned short* __restrict__ WcSwz,
                        const float* __restrict__ bc,
                        unsigned short* __restrict__ featSwz) {
  __shared__ __align__(16) unsigned short xs[2][4 * NKC * 16 * 8];  // 81,920 B
  __shared__ float fs[1024];                                        // 4 KB
  const int tid = threadIdx.x;
  const int wave = tid >> 6, lane = tid & 63;
  const int l16 = lane & 15, quad = lane >> 4;

  // zero the pad chunks once (both buffers): kc=37 upper 8B, kc=38, kc=39
  // for all (mt,l16). 2 bufs x 64 (mt,l) x 3 slots = 384 writes.
  if (tid < 384) {
    int bbuf = tid / 192, j = tid % 192;
    int s = j % 3, rem = j / 3, mt = rem >> 4, l = rem & 15;
    int kc = 37 + s;
    unsigned short* p = &xs[bbuf][((mt * NKC + kc) * 16 + l) * 8];
    if (s == 0) *reinterpret_cast<uint2*>(p + 4) = make_uint2(0, 0);
    else        *reinterpret_cast<uint4*>(p)     = make_uint4(0, 0, 0, 0);
  }

  // resident weights: breg[nt][ks] for channels wave*64 + nt*16 + l16,
  // k-slice = ks*32 + quad*8 .. +8  (WcSwz chtile = wave*4+nt, kc = ks*4+quad)
  bf16x8 breg[4][10];
  #pragma unroll
  for (int nt = 0; nt < 4; ++nt)
    #pragma unroll
    for (int ks = 0; ks < 10; ++ks)
      breg[nt][ks] = *reinterpret_cast<const bf16x8*>(
          WcSwz + (size_t)(wave * 4 + nt) * 5120 + (ks * 4 + quad) * 128 + l16 * 8);

  float bias[4];
  #pragma unroll
  for (int nt = 0; nt < 4; ++nt) bias[nt] = bc[wave * 64 + nt * 16 + l16];

  // ---- staging helpers: tile = 4800 float4 (64 rows x 75), 10 rounds of 512.
  // group A = rounds 0-4, group B = rounds 5-9 (round 9: 192 active).
  float4 pf[5];
  auto LOADG = [&](int t, int r0) {
    const float* xb = ((t & 1) ? x2 : x1) +
                      (size_t)(blockIdx.x + (t >> 1) * 256) * (L_SZ * D_SZ);
    #pragma unroll
    for (int r = 0; r < 5; ++r) {
      int idx = (r0 + r) * 512 + tid;
      if (idx < 4800) pf[r] = *reinterpret_cast<const float4*>(xb + idx * 4);
    }
  };
  auto WRITEG = [&](int bbuf, int r0) {
    #pragma unroll
    for (int r = 0; r < 5; ++r) {
      int idx = (r0 + r) * 512 + tid;
      if (idx < 4800) {
        int row = idx / 75, c4 = idx - row * 75;
        int mt = row >> 4, l = row & 15, kc = c4 >> 1;
        bf16x4 c;
        c[0] = (__bf16)pf[r].x; c[1] = (__bf16)pf[r].y;
        c[2] = (__bf16)pf[r].z; c[3] = (__bf16)pf[r].w;
        *reinterpret_cast<bf16x4*>(
            &xs[bbuf][((mt * NKC + kc) * 16 + l) * 8 + (c4 & 1) * 4]) = c;
      }
    }
  };

  // prologue: stage tile 0 into buffer 0
  LOADG(0, 0); WRITEG(0, 0);
  LOADG(0, 5); WRITEG(0, 5);
  __syncthreads();

  float e1[4];
  int buf = 0;

  for (int t = 0; t < 16; ++t) {
    if (t < 15) LOADG(t + 1, 0);           // group A loads in flight

    float erun[4] = {0.f, 0.f, 0.f, 0.f};  // relu floor

    // compute mt 0-1 from buf (linear 1KB ds_read_b128 per (mt,ks))
    #pragma unroll
    for (int mt = 0; mt < 2; ++mt) {
      f32x4 acc[4];
      #pragma unroll
      for (int nt = 0; nt < 4; ++nt)
        #pragma unroll
        for (int r = 0; r < 4; ++r) acc[nt][r] = 0.f;
      #pragma unroll
      for (int ks = 0; ks < 10; ++ks) {
        bf16x8 a = *reinterpret_cast<const bf16x8*>(
            &xs[buf][mt * 5120 + (ks * 4 + quad) * 128 + l16 * 8]);
        #pragma unroll
        for (int nt = 0; nt < 4; ++nt)
          acc[nt] = __builtin_amdgcn_mfma_f32_16x16x32_bf16(a, breg[nt][ks], acc[nt], 0, 0, 0);
      }
      #pragma unroll
      for (int nt = 0; nt < 4; ++nt)
        #pragma unroll
        for (int r = 0; r < 4; ++r)
          erun[nt] = fmaxf(erun[nt], acc[nt][r] + bias[nt]);
    }

    if (t < 15) { WRITEG(buf ^ 1, 0); LOADG(t + 1, 5); }  // write A, load B

    // compute mt 2-3
    #pragma unroll
    for (int mt = 2; mt < 4; ++mt) {
      f32x4 acc[4];
      #pragma unroll
      for (int nt = 0; nt < 4; ++nt)
        #pragma unroll
        for (int r = 0; r < 4; ++r) acc[nt][r] = 0.f;
      #pragma unroll
      for (int ks = 0; ks < 10; ++ks) {
        bf16x8 a = *reinterpret_cast<const bf16x8*>(
            &xs[buf][mt * 5120 + (ks * 4 + quad) * 128 + l16 * 8]);
        #pragma unroll
        for (int nt = 0; nt < 4; ++nt)
          acc[nt] = __builtin_amdgcn_mfma_f32_16x16x32_bf16(a, breg[nt][ks], acc[nt], 0, 0, 0);
      }
      #pragma unroll
      for (int nt = 0; nt < 4; ++nt)
        #pragma unroll
        for (int r = 0; r < 4; ++r)
          erun[nt] = fmaxf(erun[nt], acc[nt][r] + bias[nt]);
    }

    if (t < 15) WRITEG(buf ^ 1, 5);        // write B

    // finish max over words (rows live in quad x r), then e1/feat
    #pragma unroll
    for (int nt = 0; nt < 4; ++nt) {
      float v = erun[nt];
      v = fmaxf(v, __shfl_xor(v, 16));
      v = fmaxf(v, __shfl_xor(v, 32));
      if (!(t & 1)) {
        e1[nt] = v;
      } else if (quad == 0) {
        int c = wave * 64 + nt * 16 + l16;
        fs[c]       = e1[nt] - v;
        fs[512 + c] = e1[nt] * v;
      }
    }

    __syncthreads();  // buf reads + buf^1 writes done; fs visible

    if ((t & 1) && tid < 128) {  // pack feat of b into featSwz (kc = tid)
      int b = blockIdx.x + (t >> 1) * 256;
      unsigned short tmp[8];
      #pragma unroll
      for (int i = 0; i < 8; ++i) tmp[i] = f2bf(fs[tid * 8 + i]);
      *reinterpret_cast<uint4*>(featSwz + (((b >> 4) * 128 + tid) * 16 + (b & 15)) * 8) =
          *reinterpret_cast<uint4*>(tmp);
    }
    buf ^= 1;
  }
}

// ---- kernel 2: fc1+fc2 fused. pre = feat @ W1^T + b1; t = tanh(pre);
// out[b] += sum over this wave's 32 j-cols of t * W2[j]  (atomic).
__global__ __launch_bounds__(256, 4)
void fc1_kernel(const unsigned short* __restrict__ featSwz,
                const unsigned short* __restrict__ W1Swz,
                const float* __restrict__ b1, const float* __restrict__ W2,
                float* __restrict__ out) {
  const int mbase = blockIdx.x * 32;
  const int tid = threadIdx.x;
  const int wave = tid >> 6, lane = tid & 63;
  const int l16 = lane & 15, quad = lane >> 4;
  const int nbase = blockIdx.y * 128 + wave * 32;

  f32x4 acc[2][2];
  #pragma unroll
  for (int mt = 0; mt < 2; ++mt)
    #pragma unroll
    for (int nt = 0; nt < 2; ++nt)
      #pragma unroll
      for (int r = 0; r < 4; ++r) acc[mt][nt][r] = 0.f;

  #pragma unroll 4
  for (int ks = 0; ks < 32; ++ks) {
    bf16x8 a[2], bw[2];
    #pragma unroll
    for (int mt = 0; mt < 2; ++mt)
      a[mt] = *reinterpret_cast<const bf16x8*>(
          featSwz + (((size_t)(blockIdx.x * 2 + mt) * 128 + ks * 4 + quad) * 16 + l16) * 8);
    #pragma unroll
    for (int nt = 0; nt < 2; ++nt)
      bw[nt] = *reinterpret_cast<const bf16x8*>(
          W1Swz + (((size_t)(blockIdx.y * 8 + wave * 2 + nt) * 128 + ks * 4 + quad) * 16 + l16) * 8);
    #pragma unroll
    for (int mt = 0; mt < 2; ++mt)
      #pragma unroll
      for (int nt = 0; nt < 2; ++nt)
        acc[mt][nt] = __builtin_amdgcn_mfma_f32_16x16x32_bf16(a[mt], bw[nt], acc[mt][nt], 0, 0, 0);
  }

  // epilogue: tanh in fp32, dot with W2, reduce over this wave's 32 j-cols
  float c[2][4];
  #pragma unroll
  for (int mt = 0; mt < 2; ++mt)
    #pragma unroll
    for (int r = 0; r < 4; ++r) c[mt][r] = 0.f;

  #pragma unroll
  for (int nt = 0; nt < 2; ++nt) {
    int j = nbase + nt * 16 + l16;
    float bias = b1[j];
    float w2 = W2[j];
    #pragma unroll
    for (int mt = 0; mt < 2; ++mt)
      #pragma unroll
      for (int r = 0; r < 4; ++r) {
        float pre = acc[mt][nt][r] + bias;
        pre = fminf(fmaxf(pre, -15.f), 15.f);
        float ex = __expf(2.f * pre);
        c[mt][r] += w2 * ((ex - 1.f) / (ex + 1.f));
      }
  }
  #pragma unroll
  for (int off = 1; off <= 8; off <<= 1)
    #pragma unroll
    for (int mt = 0; mt < 2; ++mt)
      #pragma unroll
      for (int r = 0; r < 4; ++r)
        c[mt][r] += __shfl_xor(c[mt][r], off);

  if (l16 == 0) {
    #pragma unroll
    for (int mt = 0; mt < 2; ++mt)
      #pragma unroll
      for (int r = 0; r < 4; ++r) {
        int brow = mbase + mt * 16 + quad * 4 + r;
        atomicAdd(&out[brow], c[mt][r]);
      }
  }
}

extern "C" void kernel_launch(void* const* d_in, const int* in_sizes, int n_in,
                              void* d_out, int out_size, void* d_ws, size_t ws_size,
                              hipStream_t stream) {
  const float* x1 = (const float*)d_in[0];
  const float* x2 = (const float*)d_in[1];
  const float* Wc = (const float*)d_in[2];
  const float* bc = (const float*)d_in[3];
  const float* W1 = (const float*)d_in[4];
  const float* b1 = (const float*)d_in[5];
  const float* W2 = (const float*)d_in[6];
  const float* b2 = (const float*)d_in[7];

  char* ws = (char*)d_ws;
  unsigned short* WcSwz   = (unsigned short*)(ws);             // 327,680 B
  unsigned short* W1Swz   = (unsigned short*)(ws + 327680);    // 4,194,304 B
  unsigned short* featSwz = (unsigned short*)(ws + 4521984);   // 4,194,304 B
  // total: 8,716,288 B

  {
    int total = C_SZ * NKC + H_SZ * 128;  // 282,624
    convert_kernel<<<(total + 255) / 256, 256, 0, stream>>>(Wc, W1, b2, WcSwz, W1Swz,
                                                            (float*)d_out);
  }
  encode_feat_kernel<<<256, 512, 0, stream>>>(x1, x2, WcSwz, bc, featSwz);
  fc1_kernel<<<dim3(B_SZ / 32, H_SZ / 128), 256, 0, stream>>>(featSwz, W1Swz, b1, W2,
                                                              (float*)d_out);
}